// Round 7
// baseline (138.537 us; speedup 1.0000x reference)
//
#include <hip/hip_runtime.h>
#include <math.h>

#define DDIM 640
#define IDIM 640
#define TWO_I 1280
#define KSEL 4
#define NEXP 32
#define NTOK 64
#define NPAIR 256
#define EPSV 1e-5f
#define LIMIT 7.0f
#define CHUNK 4       // tokens per block
#define NTC 16        // token-chunk grid slots (64/CHUNK)
#define MAXRLEN 80

// ws layout (float elements):
//  tws    : [64][640]           @ 0        (40960)
//  hact   : [256][640]          @ 40960    (163840)
//  ew     : [256]               @ 204800
//  counts : [32] (int)          @ 205056
//  list   : [32][64] (int)      @ 205088
//  pexp   : [256] (int)         @ 207136
//  hpart  : [nrc][256][1280]    @ 207616   (nrc*327680; nrc = 16 or 8 per ws_size)

__global__ void k_rmsnorm(const float* __restrict__ x, const float* __restrict__ nw,
                          float* __restrict__ tws, int* __restrict__ counts) {
    const int t = blockIdx.x;
    const int tid = threadIdx.x;
    if (blockIdx.x == 0 && tid < NEXP) counts[tid] = 0;
    __shared__ float red[256];
    float s = 0.f;
    for (int d = tid; d < DDIM; d += 256) {
        float v = x[d * NTOK + t];
        s += v * v;
    }
    red[tid] = s;
    __syncthreads();
    for (int off = 128; off > 0; off >>= 1) {
        if (tid < off) red[tid] += red[tid + off];
        __syncthreads();
    }
    const float rs = 1.0f / sqrtf(red[0] * (1.0f / DDIM) + EPSV);
    for (int d = tid; d < DDIM; d += 256) {
        tws[t * DDIM + d] = x[d * NTOK + t] * rs * nw[d];
    }
}

__global__ void k_router(const float* __restrict__ tws, const float* __restrict__ gw,
                         const float* __restrict__ gb, float* __restrict__ ew,
                         int* __restrict__ counts, int* __restrict__ list,
                         int* __restrict__ pexp) {
    const int t = blockIdx.x;
    const int lane = threadIdx.x;
    __shared__ float lg[NEXP];
    if (lane < NEXP) {
        const float* g = gw + lane * DDIM;
        const float* tr = tws + t * DDIM;
        float acc = 0.f;
        for (int d = 0; d < DDIM; d += 4) {
            acc = fmaf(tr[d], g[d], acc);
            acc = fmaf(tr[d + 1], g[d + 1], acc);
            acc = fmaf(tr[d + 2], g[d + 2], acc);
            acc = fmaf(tr[d + 3], g[d + 3], acc);
        }
        lg[lane] = acc + gb[lane];
    }
    __syncthreads();
    if (lane == 0) {
        float vals[KSEL];
        int idx[KSEL];
        for (int k = 0; k < KSEL; ++k) {
            float best = -1e30f;
            int bi = 0;
            for (int e = 0; e < NEXP; ++e) {
                float v = lg[e];
                if (v > best) { best = v; bi = e; }
            }
            vals[k] = best;
            idx[k] = bi;
            lg[bi] = -1e30f;
        }
        const float m = vals[0];
        float ex[KSEL];
        float se = 0.f;
        for (int k = 0; k < KSEL; ++k) { ex[k] = __expf(vals[k] - m); se += ex[k]; }
        const float inv = 1.0f / se;
        for (int k = 0; k < KSEL; ++k) {
            const int p = t * KSEL + k;
            ew[p] = ex[k] * inv;
            pexp[p] = idx[k];
            const int slot = atomicAdd(&counts[idx[k]], 1);
            list[idx[k] * NTOK + slot] = p;
        }
    }
}

// 1D grid of NEXP*nrc*NTC blocks, 320 threads (5 waves; wave w = col-tile of 256).
// XCD-chunked swizzle: logical-consecutive blocks (same expert/rc panel, adjacent
// token-chunks) land on the SAME XCD so the tc-pair's w1 panel re-read is an L2 hit.
__global__ __launch_bounds__(320) void k_ffn1(const float* __restrict__ tws,
                                              const float* __restrict__ w1,
                                              float* __restrict__ hpart,
                                              const int* __restrict__ counts,
                                              const int* __restrict__ list,
                                              int nrcMask, int eShift, int rlen) {
    const int cpx = (int)gridDim.x >> 3;
    const int L = (blockIdx.x & 7) * cpx + (blockIdx.x >> 3);
    const int tc = L & (NTC - 1);
    const int tmp = L >> 4;
    const int rc = tmp & nrcMask;
    const int e = tmp >> eShift;

    const int cnt = counts[e];
    const int c0 = tc * CHUNK;
    if (c0 >= cnt) return;
    const int tid = threadIdx.x;
    const int wid = tid >> 6;
    const int lane = tid & 63;
    const int col0 = wid * 256 + lane * 4;   // 0..1279
    const int d0 = rc * rlen;

    __shared__ float tl[CHUNK][MAXRLEN];

    int pid[CHUNK];
#pragma unroll
    for (int s = 0; s < CHUNK; ++s) {
        int ii = c0 + s;
        ii = (ii < cnt) ? ii : c0;  // pad with chunk's first slot (identical math, dup store)
        pid[s] = list[e * NTOK + ii];
    }
#pragma unroll
    for (int s = 0; s < CHUNK; ++s)
        for (int d = tid; d < rlen; d += 320)
            tl[s][d] = tws[(pid[s] >> 2) * DDIM + d0 + d];
    __syncthreads();

    const float* wp = w1 + (size_t)e * DDIM * TWO_I + (size_t)d0 * TWO_I + col0;

    float acc[CHUNK][4];
#pragma unroll
    for (int s = 0; s < CHUNK; ++s)
#pragma unroll
        for (int c = 0; c < 4; ++c) acc[s][c] = 0.f;

    for (int rb = 0; rb < rlen; rb += 8) {
        float4 w[8];
#pragma unroll
        for (int u = 0; u < 8; ++u)
            w[u] = *reinterpret_cast<const float4*>(wp + (size_t)(rb + u) * TWO_I);
#pragma unroll
        for (int u = 0; u < 8; ++u) {
#pragma unroll
            for (int s = 0; s < CHUNK; ++s) {
                const float tv = tl[s][rb + u];
                acc[s][0] = fmaf(tv, w[u].x, acc[s][0]);
                acc[s][1] = fmaf(tv, w[u].y, acc[s][1]);
                acc[s][2] = fmaf(tv, w[u].z, acc[s][2]);
                acc[s][3] = fmaf(tv, w[u].w, acc[s][3]);
            }
        }
    }

#pragma unroll
    for (int s = 0; s < CHUNK; ++s) {
        float4 v = make_float4(acc[s][0], acc[s][1], acc[s][2], acc[s][3]);
        *reinterpret_cast<float4*>(&hpart[((size_t)rc * NPAIR + pid[s]) * TWO_I + col0]) = v;
    }
}

// grid (256) x 256: reduce rc partials, add bias, activation -> hact
__global__ void k_reduce1(const float* __restrict__ hpart, const float* __restrict__ b1,
                          const int* __restrict__ pexp, float* __restrict__ hact, int nrc) {
    const int p = blockIdx.x;
    const int e = pexp[p];
    for (int i = threadIdx.x; i < IDIM; i += 256) {
        float g = 0.f, l = 0.f;
        for (int rc = 0; rc < nrc; ++rc) {
            g += hpart[((size_t)rc * NPAIR + p) * TWO_I + i];
            l += hpart[((size_t)rc * NPAIR + p) * TWO_I + i + IDIM];
        }
        float hg = fminf(g + b1[e * TWO_I + i], LIMIT);
        float hl = l + b1[e * TWO_I + IDIM + i];
        hl = fminf(fmaxf(hl, -LIMIT), LIMIT);
        const float sig = 1.0f / (1.0f + __expf(-1.702f * hg));
        hact[(size_t)p * IDIM + i] = hg * sig * (hl + 1.0f);
    }
}

// Same 1D swizzled grid; 320 threads, lane owns float2 (640 cols = 320 threads).
__global__ __launch_bounds__(320) void k_ffn2(const float* __restrict__ hact,
                                              const float* __restrict__ w2,
                                              float* __restrict__ hpart2,
                                              const int* __restrict__ counts,
                                              const int* __restrict__ list,
                                              int nrcMask, int eShift, int rlen) {
    const int cpx = (int)gridDim.x >> 3;
    const int L = (blockIdx.x & 7) * cpx + (blockIdx.x >> 3);
    const int tc = L & (NTC - 1);
    const int tmp = L >> 4;
    const int rc = tmp & nrcMask;
    const int e = tmp >> eShift;

    const int cnt = counts[e];
    const int c0 = tc * CHUNK;
    if (c0 >= cnt) return;
    const int tid = threadIdx.x;
    const int col0 = tid * 2;                // 0..638
    const int i0 = rc * rlen;

    __shared__ float tl[CHUNK][MAXRLEN];

    int pid[CHUNK];
#pragma unroll
    for (int s = 0; s < CHUNK; ++s) {
        int ii = c0 + s;
        ii = (ii < cnt) ? ii : c0;
        pid[s] = list[e * NTOK + ii];
    }
#pragma unroll
    for (int s = 0; s < CHUNK; ++s)
        for (int d = tid; d < rlen; d += 320)
            tl[s][d] = hact[(size_t)pid[s] * IDIM + i0 + d];
    __syncthreads();

    const float* wp = w2 + (size_t)e * IDIM * DDIM + (size_t)i0 * DDIM + col0;

    float acc[CHUNK][2];
#pragma unroll
    for (int s = 0; s < CHUNK; ++s) { acc[s][0] = 0.f; acc[s][1] = 0.f; }

    for (int rb = 0; rb < rlen; rb += 8) {
        float2 w[8];
#pragma unroll
        for (int u = 0; u < 8; ++u)
            w[u] = *reinterpret_cast<const float2*>(wp + (size_t)(rb + u) * DDIM);
#pragma unroll
        for (int u = 0; u < 8; ++u) {
#pragma unroll
            for (int s = 0; s < CHUNK; ++s) {
                const float hv = tl[s][rb + u];
                acc[s][0] = fmaf(hv, w[u].x, acc[s][0]);
                acc[s][1] = fmaf(hv, w[u].y, acc[s][1]);
            }
        }
    }

#pragma unroll
    for (int s = 0; s < CHUNK; ++s) {
        float2 v = make_float2(acc[s][0], acc[s][1]);
        *reinterpret_cast<float2*>(&hpart2[((size_t)rc * NPAIR + pid[s]) * DDIM + col0]) = v;
    }
}

// grid (64) x 256: reduce rc partials of ffn2, add bias, weight by ew, sum k, residual
__global__ void k_final(const float* __restrict__ x, const float* __restrict__ hpart2,
                        const float* __restrict__ b2, const float* __restrict__ ew,
                        const int* __restrict__ pexp, float* __restrict__ out, int nrc) {
    const int t = blockIdx.x;
    for (int d = threadIdx.x; d < DDIM; d += 256) {
        float v = x[d * NTOK + t];
#pragma unroll
        for (int k = 0; k < KSEL; ++k) {
            const int p = t * KSEL + k;
            const int e = pexp[p];
            float s = 0.f;
            for (int rc = 0; rc < nrc; ++rc)
                s += hpart2[((size_t)rc * NPAIR + p) * DDIM + d];
            v += (s + b2[e * DDIM + d]) * ew[p];
        }
        out[d * NTOK + t] = v;
    }
}

extern "C" void kernel_launch(void* const* d_in, const int* in_sizes, int n_in,
                              void* d_out, int out_size, void* d_ws, size_t ws_size,
                              hipStream_t stream) {
    const float* x  = (const float*)d_in[0];
    const float* nw = (const float*)d_in[1];
    const float* gw = (const float*)d_in[2];
    const float* gb = (const float*)d_in[3];
    const float* w1 = (const float*)d_in[4];
    const float* b1 = (const float*)d_in[5];
    const float* w2 = (const float*)d_in[6];
    const float* b2 = (const float*)d_in[7];
    float* out = (float*)d_out;

    float* ws    = (float*)d_ws;
    float* tws   = ws;                   // 40960
    float* hact  = ws + 40960;           // 163840
    float* ew    = ws + 204800;          // 256
    int* counts  = (int*)(ws + 205056);  // 32
    int* list    = (int*)(ws + 205088);  // 2048
    int* pexp    = (int*)(ws + 207136);  // 256
    float* hpart = ws + 207616;          // nrc*327680

    const size_t need16 = ((size_t)207616 + (size_t)16 * 327680) * 4;
    const int nrc = (ws_size >= need16) ? 16 : 8;
    const int eShift = (nrc == 16) ? 4 : 3;
    const int rlen = DDIM / nrc;
    const int nblk = NEXP * nrc * NTC;   // 8192 or 4096, both divisible by 8

    hipLaunchKernelGGL(k_rmsnorm, dim3(NTOK), dim3(256), 0, stream, x, nw, tws, counts);
    hipLaunchKernelGGL(k_router, dim3(NTOK), dim3(64), 0, stream, tws, gw, gb, ew, counts, list, pexp);
    hipLaunchKernelGGL(k_ffn1, dim3(nblk), dim3(320), 0, stream, tws, w1, hpart, counts, list,
                       nrc - 1, eShift, rlen);
    hipLaunchKernelGGL(k_reduce1, dim3(NPAIR), dim3(256), 0, stream, hpart, b1, pexp, hact, nrc);
    hipLaunchKernelGGL(k_ffn2, dim3(nblk), dim3(320), 0, stream, hact, w2, hpart, counts, list,
                       nrc - 1, eShift, rlen);
    hipLaunchKernelGGL(k_final, dim3(NTOK), dim3(256), 0, stream, x, hpart, b2, ew, pexp, out, nrc);
}

// Round 8
// 86.028 us; speedup vs baseline: 1.6104x; 1.6104x over previous
//
#include <hip/hip_runtime.h>
#include <math.h>

#define DDIM 640
#define IDIM 640
#define TWO_I 1280
#define KSEL 4
#define NEXP 32
#define NTOK 64
#define NPAIR 256
#define EPSV 1e-5f
#define LIMIT 7.0f
#define CHUNK 8
#define RC 8          // reduction-dim chunks
#define RLEN 80       // rows per chunk (640/8)

#define WAITVM(n) asm volatile("s_waitcnt vmcnt(" #n ")" ::: "memory")
#define RAWBAR() __builtin_amdgcn_s_barrier()
#define GLL(gp, lp)                                                            \
    __builtin_amdgcn_global_load_lds(                                          \
        (const __attribute__((address_space(1))) void*)(gp),                   \
        (__attribute__((address_space(3))) void*)(lp), 16, 0, 0)

// ws layout (float elements):
//  tws    : [64][640]            @ 0         (40960)
//  hact   : [256][640]           @ 40960     (163840)
//  hpart  : [8][256][1280]       @ 204800    (2621440)
//  ew     : [256]                @ 2826240
//  counts : [32] (int)           @ 2826496
//  list   : [32][64] (int)       @ 2826528
//  pexp   : [256] (int)          @ 2828576

__global__ void k_rmsnorm(const float* __restrict__ x, const float* __restrict__ nw,
                          float* __restrict__ tws, int* __restrict__ counts) {
    const int t = blockIdx.x;
    const int tid = threadIdx.x;
    if (blockIdx.x == 0 && tid < NEXP) counts[tid] = 0;
    __shared__ float red[256];
    float s = 0.f;
    for (int d = tid; d < DDIM; d += 256) {
        float v = x[d * NTOK + t];
        s += v * v;
    }
    red[tid] = s;
    __syncthreads();
    for (int off = 128; off > 0; off >>= 1) {
        if (tid < off) red[tid] += red[tid + off];
        __syncthreads();
    }
    const float rs = 1.0f / sqrtf(red[0] * (1.0f / DDIM) + EPSV);
    for (int d = tid; d < DDIM; d += 256) {
        tws[t * DDIM + d] = x[d * NTOK + t] * rs * nw[d];
    }
}

__global__ void k_router(const float* __restrict__ tws, const float* __restrict__ gw,
                         const float* __restrict__ gb, float* __restrict__ ew,
                         int* __restrict__ counts, int* __restrict__ list,
                         int* __restrict__ pexp) {
    const int t = blockIdx.x;
    const int lane = threadIdx.x;
    __shared__ float lg[NEXP];
    if (lane < NEXP) {
        const float* g = gw + lane * DDIM;
        const float* tr = tws + t * DDIM;
        float acc = 0.f;
        for (int d = 0; d < DDIM; d += 4) {
            acc = fmaf(tr[d], g[d], acc);
            acc = fmaf(tr[d + 1], g[d + 1], acc);
            acc = fmaf(tr[d + 2], g[d + 2], acc);
            acc = fmaf(tr[d + 3], g[d + 3], acc);
        }
        lg[lane] = acc + gb[lane];
    }
    __syncthreads();
    if (lane == 0) {
        float vals[KSEL];
        int idx[KSEL];
        for (int k = 0; k < KSEL; ++k) {
            float best = -1e30f;
            int bi = 0;
            for (int e = 0; e < NEXP; ++e) {
                float v = lg[e];
                if (v > best) { best = v; bi = e; }
            }
            vals[k] = best;
            idx[k] = bi;
            lg[bi] = -1e30f;
        }
        const float m = vals[0];
        float ex[KSEL];
        float se = 0.f;
        for (int k = 0; k < KSEL; ++k) { ex[k] = __expf(vals[k] - m); se += ex[k]; }
        const float inv = 1.0f / se;
        for (int k = 0; k < KSEL; ++k) {
            const int p = t * KSEL + k;
            ew[p] = ex[k] * inv;
            pexp[p] = idx[k];
            const int slot = atomicAdd(&counts[idx[k]], 1);
            list[idx[k] * NTOK + slot] = p;
        }
    }
}

// grid (32, 64): x = expert, y = rc*8 + tc. Block = 320 threads (5 waves).
// The weight panel (80 rows x 1280 cols) is streamed SEQUENTIALLY into LDS in
// 8-row / 40KB double-buffered tiles via global_load_lds (wave w owns contiguous
// 8KB per tile). Compute reads the tile from LDS (strides free). Raw s_barrier +
// counted vmcnt keep 8-16 x 1KB outstanding per wave across phases.
__global__ __launch_bounds__(320, 1) void k_ffn1(const float* __restrict__ tws,
                                                 const float* __restrict__ w1,
                                                 float* __restrict__ hpart,
                                                 const int* __restrict__ counts,
                                                 const int* __restrict__ list) {
    const int e = blockIdx.x;
    const int rc = blockIdx.y >> 3;
    const int tc = blockIdx.y & 7;
    const int cnt = counts[e];
    const int c0 = tc * CHUNK;
    if (c0 >= cnt) return;
    const int tid = threadIdx.x;
    const int wid = tid >> 6;
    const int lane = tid & 63;
    const int col0 = wid * 256 + lane * 4;   // 0..1279
    const int d0 = rc * RLEN;

    __shared__ float wlds[2][8 * TWO_I];   // 2 x 40 KB
    __shared__ float tl[CHUNK][RLEN];

    int pid[CHUNK];
#pragma unroll
    for (int s = 0; s < CHUNK; ++s) {
        int ii = c0 + s;
        ii = (ii < cnt) ? ii : c0;  // pad with chunk's first slot (identical math, dup store)
        pid[s] = list[e * NTOK + ii];
    }
#pragma unroll
    for (int s = 0; s < CHUNK; ++s)
        for (int d = tid; d < RLEN; d += 320)
            tl[s][d] = tws[(pid[s] >> 2) * DDIM + d0 + d];
    __syncthreads();   // drains vmcnt; pipeline starts after this

    const float* wpanel = w1 + (size_t)e * DDIM * TWO_I + (size_t)d0 * TWO_I;

    float acc[CHUNK][4];
#pragma unroll
    for (int s = 0; s < CHUNK; ++s)
#pragma unroll
        for (int c = 0; c < 4; ++c) acc[s][c] = 0.f;

    // prologue: stage phase 0 into buf 0 (8 x 1KB per wave)
#pragma unroll
    for (int k = 0; k < 8; ++k)
        GLL(wpanel + wid * 2048 + k * 256 + lane * 4, &wlds[0][wid * 2048 + k * 256]);

    for (int t = 0; t < 10; ++t) {
        const int cur = t & 1;
        if (t + 1 < 10) {
            const int nxt = (t + 1) & 1;
            const float* gsrc = wpanel + (size_t)(t + 1) * 8 * TWO_I;
#pragma unroll
            for (int k = 0; k < 8; ++k)
                GLL(gsrc + wid * 2048 + k * 256 + lane * 4, &wlds[nxt][wid * 2048 + k * 256]);
            WAITVM(8);   // cur's 8 done; nxt's 8 still in flight
        } else {
            WAITVM(0);
        }
        RAWBAR();        // all waves' cur tile resident
#pragma unroll
        for (int r = 0; r < 8; ++r) {
            const float4 w = *reinterpret_cast<const float4*>(&wlds[cur][r * TWO_I + col0]);
            const int row = t * 8 + r;
#pragma unroll
            for (int s = 0; s < CHUNK; ++s) {
                const float tv = tl[s][row];
                acc[s][0] = fmaf(tv, w.x, acc[s][0]);
                acc[s][1] = fmaf(tv, w.y, acc[s][1]);
                acc[s][2] = fmaf(tv, w.z, acc[s][2]);
                acc[s][3] = fmaf(tv, w.w, acc[s][3]);
            }
        }
        RAWBAR();        // everyone done reading cur before it's overwritten
    }

#pragma unroll
    for (int s = 0; s < CHUNK; ++s) {
        float4 v = make_float4(acc[s][0], acc[s][1], acc[s][2], acc[s][3]);
        *reinterpret_cast<float4*>(&hpart[((size_t)rc * NPAIR + pid[s]) * TWO_I + col0]) = v;
    }
}

// grid (256) x 256: reduce rc partials, add bias, activation -> hact
__global__ void k_reduce1(const float* __restrict__ hpart, const float* __restrict__ b1,
                          const int* __restrict__ pexp, float* __restrict__ hact) {
    const int p = blockIdx.x;
    const int e = pexp[p];
    for (int i = threadIdx.x; i < IDIM; i += 256) {
        float g = 0.f, l = 0.f;
#pragma unroll
        for (int rc = 0; rc < RC; ++rc) {
            g += hpart[((size_t)rc * NPAIR + p) * TWO_I + i];
            l += hpart[((size_t)rc * NPAIR + p) * TWO_I + i + IDIM];
        }
        float hg = fminf(g + b1[e * TWO_I + i], LIMIT);
        float hl = l + b1[e * TWO_I + IDIM + i];
        hl = fminf(fmaxf(hl, -LIMIT), LIMIT);
        const float sig = 1.0f / (1.0f + __expf(-1.702f * hg));
        hact[(size_t)p * IDIM + i] = hg * sig * (hl + 1.0f);
    }
}

// grid (32, 64): same structure over w2; 16-row / 40KB tiles, 5 phases.
// 320 threads, lane owns 2 cols (640 = 320*2).
__global__ __launch_bounds__(320, 1) void k_ffn2(const float* __restrict__ hact,
                                                 const float* __restrict__ w2,
                                                 float* __restrict__ hpart2,
                                                 const int* __restrict__ counts,
                                                 const int* __restrict__ list) {
    const int e = blockIdx.x;
    const int rc = blockIdx.y >> 3;
    const int tc = blockIdx.y & 7;
    const int cnt = counts[e];
    const int c0 = tc * CHUNK;
    if (c0 >= cnt) return;
    const int tid = threadIdx.x;
    const int wid = tid >> 6;
    const int lane = tid & 63;
    const int col0 = tid * 2;                // 0..638
    const int i0 = rc * RLEN;

    __shared__ float wlds[2][16 * DDIM];   // 2 x 40 KB
    __shared__ float tl[CHUNK][RLEN];

    int pid[CHUNK];
#pragma unroll
    for (int s = 0; s < CHUNK; ++s) {
        int ii = c0 + s;
        ii = (ii < cnt) ? ii : c0;
        pid[s] = list[e * NTOK + ii];
    }
#pragma unroll
    for (int s = 0; s < CHUNK; ++s)
        for (int d = tid; d < RLEN; d += 320)
            tl[s][d] = hact[(size_t)pid[s] * IDIM + i0 + d];
    __syncthreads();

    const float* wpanel = w2 + (size_t)e * IDIM * DDIM + (size_t)i0 * DDIM;

    float acc[CHUNK][2];
#pragma unroll
    for (int s = 0; s < CHUNK; ++s) { acc[s][0] = 0.f; acc[s][1] = 0.f; }

#pragma unroll
    for (int k = 0; k < 8; ++k)
        GLL(wpanel + wid * 2048 + k * 256 + lane * 4, &wlds[0][wid * 2048 + k * 256]);

    for (int t = 0; t < 5; ++t) {
        const int cur = t & 1;
        if (t + 1 < 5) {
            const int nxt = (t + 1) & 1;
            const float* gsrc = wpanel + (size_t)(t + 1) * 16 * DDIM;
#pragma unroll
            for (int k = 0; k < 8; ++k)
                GLL(gsrc + wid * 2048 + k * 256 + lane * 4, &wlds[nxt][wid * 2048 + k * 256]);
            WAITVM(8);
        } else {
            WAITVM(0);
        }
        RAWBAR();
#pragma unroll
        for (int r = 0; r < 16; ++r) {
            const float2 w = *reinterpret_cast<const float2*>(&wlds[cur][r * DDIM + col0]);
            const int row = t * 16 + r;
#pragma unroll
            for (int s = 0; s < CHUNK; ++s) {
                const float hv = tl[s][row];
                acc[s][0] = fmaf(hv, w.x, acc[s][0]);
                acc[s][1] = fmaf(hv, w.y, acc[s][1]);
            }
        }
        RAWBAR();
    }

#pragma unroll
    for (int s = 0; s < CHUNK; ++s) {
        float2 v = make_float2(acc[s][0], acc[s][1]);
        *reinterpret_cast<float2*>(&hpart2[((size_t)rc * NPAIR + pid[s]) * DDIM + col0]) = v;
    }
}

// grid (64) x 256: reduce rc partials of ffn2, add bias, weight by ew, sum k, residual
__global__ void k_final(const float* __restrict__ x, const float* __restrict__ hpart2,
                        const float* __restrict__ b2, const float* __restrict__ ew,
                        const int* __restrict__ pexp, float* __restrict__ out) {
    const int t = blockIdx.x;
    for (int d = threadIdx.x; d < DDIM; d += 256) {
        float v = x[d * NTOK + t];
#pragma unroll
        for (int k = 0; k < KSEL; ++k) {
            const int p = t * KSEL + k;
            const int e = pexp[p];
            float s = 0.f;
#pragma unroll
            for (int rc = 0; rc < RC; ++rc)
                s += hpart2[((size_t)rc * NPAIR + p) * DDIM + d];
            v += (s + b2[e * DDIM + d]) * ew[p];
        }
        out[d * NTOK + t] = v;
    }
}

extern "C" void kernel_launch(void* const* d_in, const int* in_sizes, int n_in,
                              void* d_out, int out_size, void* d_ws, size_t ws_size,
                              hipStream_t stream) {
    const float* x  = (const float*)d_in[0];
    const float* nw = (const float*)d_in[1];
    const float* gw = (const float*)d_in[2];
    const float* gb = (const float*)d_in[3];
    const float* w1 = (const float*)d_in[4];
    const float* b1 = (const float*)d_in[5];
    const float* w2 = (const float*)d_in[6];
    const float* b2 = (const float*)d_in[7];
    float* out = (float*)d_out;

    float* ws    = (float*)d_ws;
    float* tws   = ws;                    // 40960
    float* hact  = ws + 40960;            // 163840
    float* hpart = ws + 204800;           // 2621440 (ffn1), reused for ffn2
    float* ew    = ws + 2826240;          // 256
    int* counts  = (int*)(ws + 2826496);  // 32
    int* list    = (int*)(ws + 2826528);  // 2048
    int* pexp    = (int*)(ws + 2828576);  // 256

    hipLaunchKernelGGL(k_rmsnorm, dim3(NTOK), dim3(256), 0, stream, x, nw, tws, counts);
    hipLaunchKernelGGL(k_router, dim3(NTOK), dim3(64), 0, stream, tws, gw, gb, ew, counts, list, pexp);
    hipLaunchKernelGGL(k_ffn1, dim3(NEXP, 64), dim3(320), 0, stream, tws, w1, hpart, counts, list);
    hipLaunchKernelGGL(k_reduce1, dim3(NPAIR), dim3(256), 0, stream, hpart, b1, pexp, hact);
    hipLaunchKernelGGL(k_ffn2, dim3(NEXP, 64), dim3(320), 0, stream, hact, w2, hpart, counts, list);
    hipLaunchKernelGGL(k_final, dim3(NTOK), dim3(256), 0, stream, x, hpart, b2, ew, pexp, out);
}

// Round 9
// 80.600 us; speedup vs baseline: 1.7188x; 1.0674x over previous
//
#include <hip/hip_runtime.h>
#include <math.h>

#define DDIM 640
#define IDIM 640
#define TWO_I 1280
#define KSEL 4
#define NEXP 32
#define NTOK 64
#define NPAIR 256
#define EPSV 1e-5f
#define LIMIT 7.0f
#define CHUNK 16      // tokens per pass (in registers)
#define RC 8          // reduction-dim chunks
#define RLEN 80       // rows per chunk (640/8)

#define WAITVM(n) asm volatile("s_waitcnt vmcnt(" #n ")" ::: "memory")
#define RAWBAR() __builtin_amdgcn_s_barrier()
#define GLL(gp, lp)                                                            \
    __builtin_amdgcn_global_load_lds(                                          \
        (const __attribute__((address_space(1))) void*)(gp),                   \
        (__attribute__((address_space(3))) void*)(lp), 16, 0, 0)

// ws layout (float elements):
//  tws    : [64][640]            @ 0         (40960)
//  hact   : [256][640]           @ 40960     (163840)
//  hpart  : [8][256][1280]       @ 204800    (2621440)
//  ew     : [256]                @ 2826240
//  counts : [32] (int)           @ 2826496
//  list   : [32][64] (int)       @ 2826528
//  pexp   : [256] (int)          @ 2828576

__global__ void k_rmsnorm(const float* __restrict__ x, const float* __restrict__ nw,
                          float* __restrict__ tws, int* __restrict__ counts) {
    const int t = blockIdx.x;
    const int tid = threadIdx.x;
    if (blockIdx.x == 0 && tid < NEXP) counts[tid] = 0;
    __shared__ float red[256];
    float s = 0.f;
    for (int d = tid; d < DDIM; d += 256) {
        float v = x[d * NTOK + t];
        s += v * v;
    }
    red[tid] = s;
    __syncthreads();
    for (int off = 128; off > 0; off >>= 1) {
        if (tid < off) red[tid] += red[tid + off];
        __syncthreads();
    }
    const float rs = 1.0f / sqrtf(red[0] * (1.0f / DDIM) + EPSV);
    for (int d = tid; d < DDIM; d += 256) {
        tws[t * DDIM + d] = x[d * NTOK + t] * rs * nw[d];
    }
}

__global__ void k_router(const float* __restrict__ tws, const float* __restrict__ gw,
                         const float* __restrict__ gb, float* __restrict__ ew,
                         int* __restrict__ counts, int* __restrict__ list,
                         int* __restrict__ pexp) {
    const int t = blockIdx.x;
    const int lane = threadIdx.x;
    __shared__ float lg[NEXP];
    if (lane < NEXP) {
        const float* g = gw + lane * DDIM;
        const float* tr = tws + t * DDIM;
        float acc = 0.f;
        for (int d = 0; d < DDIM; d += 4) {
            acc = fmaf(tr[d], g[d], acc);
            acc = fmaf(tr[d + 1], g[d + 1], acc);
            acc = fmaf(tr[d + 2], g[d + 2], acc);
            acc = fmaf(tr[d + 3], g[d + 3], acc);
        }
        lg[lane] = acc + gb[lane];
    }
    __syncthreads();
    if (lane == 0) {
        float vals[KSEL];
        int idx[KSEL];
        for (int k = 0; k < KSEL; ++k) {
            float best = -1e30f;
            int bi = 0;
            for (int e = 0; e < NEXP; ++e) {
                float v = lg[e];
                if (v > best) { best = v; bi = e; }
            }
            vals[k] = best;
            idx[k] = bi;
            lg[bi] = -1e30f;
        }
        const float m = vals[0];
        float ex[KSEL];
        float se = 0.f;
        for (int k = 0; k < KSEL; ++k) { ex[k] = __expf(vals[k] - m); se += ex[k]; }
        const float inv = 1.0f / se;
        for (int k = 0; k < KSEL; ++k) {
            const int p = t * KSEL + k;
            ew[p] = ex[k] * inv;
            pexp[p] = idx[k];
            const int slot = atomicAdd(&counts[idx[k]], 1);
            list[idx[k] * NTOK + slot] = p;
        }
    }
}

// grid (RC=8, NEXP=32) = 256 blocks — EVERY block has work, 1 block/CU.
// 320 threads (5 waves; wave w = 256-col tile). Token chunks of 16 looped
// inside; weight panel streamed seq. via global_load_lds, double-buffered.
__global__ __launch_bounds__(320, 1) void k_ffn1(const float* __restrict__ tws,
                                                 const float* __restrict__ w1,
                                                 float* __restrict__ hpart,
                                                 const int* __restrict__ counts,
                                                 const int* __restrict__ list) {
    const int rc = blockIdx.x;
    const int e = blockIdx.y;
    const int cnt = counts[e];
    const int tid = threadIdx.x;
    const int wid = tid >> 6;
    const int lane = tid & 63;
    const int col0 = wid * 256 + lane * 4;   // 0..1279
    const int d0 = rc * RLEN;

    __shared__ float wlds[2][8 * TWO_I];   // 2 x 40 KB
    __shared__ float tl[CHUNK][RLEN];      // 5 KB

    const float* wpanel = w1 + (size_t)e * DDIM * TWO_I + (size_t)d0 * TWO_I;

    for (int c0 = 0; c0 < cnt; c0 += CHUNK) {
        int pid[CHUNK];
#pragma unroll
        for (int s = 0; s < CHUNK; ++s) {
            int ii = c0 + s;
            ii = (ii < cnt) ? ii : c0;  // pad: duplicate math, duplicate same-value store
            pid[s] = list[e * NTOK + ii];
        }
        __syncthreads();   // previous pass fully done before tl overwrite
#pragma unroll
        for (int s = 0; s < CHUNK; ++s)
            for (int d = tid; d < RLEN; d += 320)
                tl[s][d] = tws[(pid[s] >> 2) * DDIM + d0 + d];
        __syncthreads();

        float acc[CHUNK][4];
#pragma unroll
        for (int s = 0; s < CHUNK; ++s)
#pragma unroll
            for (int c = 0; c < 4; ++c) acc[s][c] = 0.f;

#pragma unroll
        for (int k = 0; k < 8; ++k)
            GLL(wpanel + wid * 2048 + k * 256 + lane * 4, &wlds[0][wid * 2048 + k * 256]);

        for (int t = 0; t < 10; ++t) {
            const int cur = t & 1;
            if (t + 1 < 10) {
                const int nxt = (t + 1) & 1;
                const float* gsrc = wpanel + (size_t)(t + 1) * 8 * TWO_I;
#pragma unroll
                for (int k = 0; k < 8; ++k)
                    GLL(gsrc + wid * 2048 + k * 256 + lane * 4, &wlds[nxt][wid * 2048 + k * 256]);
                WAITVM(8);
            } else {
                WAITVM(0);
            }
            RAWBAR();
#pragma unroll
            for (int r = 0; r < 8; ++r) {
                const float4 w = *reinterpret_cast<const float4*>(&wlds[cur][r * TWO_I + col0]);
                const int row = t * 8 + r;
#pragma unroll
                for (int s = 0; s < CHUNK; ++s) {
                    const float tv = tl[s][row];
                    acc[s][0] = fmaf(tv, w.x, acc[s][0]);
                    acc[s][1] = fmaf(tv, w.y, acc[s][1]);
                    acc[s][2] = fmaf(tv, w.z, acc[s][2]);
                    acc[s][3] = fmaf(tv, w.w, acc[s][3]);
                }
            }
            RAWBAR();
        }

#pragma unroll
        for (int s = 0; s < CHUNK; ++s) {
            float4 v = make_float4(acc[s][0], acc[s][1], acc[s][2], acc[s][3]);
            *reinterpret_cast<float4*>(&hpart[((size_t)rc * NPAIR + pid[s]) * TWO_I + col0]) = v;
        }
    }
}

// grid (256) x 256: reduce rc partials, add bias, activation -> hact
__global__ void k_reduce1(const float* __restrict__ hpart, const float* __restrict__ b1,
                          const int* __restrict__ pexp, float* __restrict__ hact) {
    const int p = blockIdx.x;
    const int e = pexp[p];
    for (int i = threadIdx.x; i < IDIM; i += 256) {
        float g = 0.f, l = 0.f;
#pragma unroll
        for (int rc = 0; rc < RC; ++rc) {
            g += hpart[((size_t)rc * NPAIR + p) * TWO_I + i];
            l += hpart[((size_t)rc * NPAIR + p) * TWO_I + i + IDIM];
        }
        float hg = fminf(g + b1[e * TWO_I + i], LIMIT);
        float hl = l + b1[e * TWO_I + IDIM + i];
        hl = fminf(fmaxf(hl, -LIMIT), LIMIT);
        const float sig = 1.0f / (1.0f + __expf(-1.702f * hg));
        hact[(size_t)p * IDIM + i] = hg * sig * (hl + 1.0f);
    }
}

// grid (RC=8, NEXP=32): same structure over w2; 16-row / 40KB tiles, 5 phases.
// 320 threads, lane owns 2 cols (640 = 320*2).
__global__ __launch_bounds__(320, 1) void k_ffn2(const float* __restrict__ hact,
                                                 const float* __restrict__ w2,
                                                 float* __restrict__ hpart2,
                                                 const int* __restrict__ counts,
                                                 const int* __restrict__ list) {
    const int rc = blockIdx.x;
    const int e = blockIdx.y;
    const int cnt = counts[e];
    const int tid = threadIdx.x;
    const int wid = tid >> 6;
    const int lane = tid & 63;
    const int col0 = tid * 2;                // 0..638
    const int i0 = rc * RLEN;

    __shared__ float wlds[2][16 * DDIM];   // 2 x 40 KB
    __shared__ float tl[CHUNK][RLEN];

    const float* wpanel = w2 + (size_t)e * IDIM * DDIM + (size_t)i0 * DDIM;

    for (int c0 = 0; c0 < cnt; c0 += CHUNK) {
        int pid[CHUNK];
#pragma unroll
        for (int s = 0; s < CHUNK; ++s) {
            int ii = c0 + s;
            ii = (ii < cnt) ? ii : c0;
            pid[s] = list[e * NTOK + ii];
        }
        __syncthreads();
#pragma unroll
        for (int s = 0; s < CHUNK; ++s)
            for (int d = tid; d < RLEN; d += 320)
                tl[s][d] = hact[(size_t)pid[s] * IDIM + i0 + d];
        __syncthreads();

        float acc[CHUNK][2];
#pragma unroll
        for (int s = 0; s < CHUNK; ++s) { acc[s][0] = 0.f; acc[s][1] = 0.f; }

#pragma unroll
        for (int k = 0; k < 8; ++k)
            GLL(wpanel + wid * 2048 + k * 256 + lane * 4, &wlds[0][wid * 2048 + k * 256]);

        for (int t = 0; t < 5; ++t) {
            const int cur = t & 1;
            if (t + 1 < 5) {
                const int nxt = (t + 1) & 1;
                const float* gsrc = wpanel + (size_t)(t + 1) * 16 * DDIM;
#pragma unroll
                for (int k = 0; k < 8; ++k)
                    GLL(gsrc + wid * 2048 + k * 256 + lane * 4, &wlds[nxt][wid * 2048 + k * 256]);
                WAITVM(8);
            } else {
                WAITVM(0);
            }
            RAWBAR();
#pragma unroll
            for (int r = 0; r < 16; ++r) {
                const float2 w = *reinterpret_cast<const float2*>(&wlds[cur][r * DDIM + col0]);
                const int row = t * 16 + r;
#pragma unroll
                for (int s = 0; s < CHUNK; ++s) {
                    const float hv = tl[s][row];
                    acc[s][0] = fmaf(hv, w.x, acc[s][0]);
                    acc[s][1] = fmaf(hv, w.y, acc[s][1]);
                }
            }
            RAWBAR();
        }

#pragma unroll
        for (int s = 0; s < CHUNK; ++s) {
            float2 v = make_float2(acc[s][0], acc[s][1]);
            *reinterpret_cast<float2*>(&hpart2[((size_t)rc * NPAIR + pid[s]) * DDIM + col0]) = v;
        }
    }
}

// grid (64) x 256: reduce rc partials of ffn2, add bias, weight by ew, sum k, residual
__global__ void k_final(const float* __restrict__ x, const float* __restrict__ hpart2,
                        const float* __restrict__ b2, const float* __restrict__ ew,
                        const int* __restrict__ pexp, float* __restrict__ out) {
    const int t = blockIdx.x;
    for (int d = threadIdx.x; d < DDIM; d += 256) {
        float v = x[d * NTOK + t];
#pragma unroll
        for (int k = 0; k < KSEL; ++k) {
            const int p = t * KSEL + k;
            const int e = pexp[p];
            float s = 0.f;
#pragma unroll
            for (int rc = 0; rc < RC; ++rc)
                s += hpart2[((size_t)rc * NPAIR + p) * DDIM + d];
            v += (s + b2[e * DDIM + d]) * ew[p];
        }
        out[d * NTOK + t] = v;
    }
}

extern "C" void kernel_launch(void* const* d_in, const int* in_sizes, int n_in,
                              void* d_out, int out_size, void* d_ws, size_t ws_size,
                              hipStream_t stream) {
    const float* x  = (const float*)d_in[0];
    const float* nw = (const float*)d_in[1];
    const float* gw = (const float*)d_in[2];
    const float* gb = (const float*)d_in[3];
    const float* w1 = (const float*)d_in[4];
    const float* b1 = (const float*)d_in[5];
    const float* w2 = (const float*)d_in[6];
    const float* b2 = (const float*)d_in[7];
    float* out = (float*)d_out;

    float* ws    = (float*)d_ws;
    float* tws   = ws;                    // 40960
    float* hact  = ws + 40960;            // 163840
    float* hpart = ws + 204800;           // 2621440 (ffn1), reused for ffn2
    float* ew    = ws + 2826240;          // 256
    int* counts  = (int*)(ws + 2826496);  // 32
    int* list    = (int*)(ws + 2826528);  // 2048
    int* pexp    = (int*)(ws + 2828576);  // 256

    hipLaunchKernelGGL(k_rmsnorm, dim3(NTOK), dim3(256), 0, stream, x, nw, tws, counts);
    hipLaunchKernelGGL(k_router, dim3(NTOK), dim3(64), 0, stream, tws, gw, gb, ew, counts, list, pexp);
    hipLaunchKernelGGL(k_ffn1, dim3(RC, NEXP), dim3(320), 0, stream, tws, w1, hpart, counts, list);
    hipLaunchKernelGGL(k_reduce1, dim3(NPAIR), dim3(256), 0, stream, hpart, b1, pexp, hact);
    hipLaunchKernelGGL(k_ffn2, dim3(RC, NEXP), dim3(320), 0, stream, hact, w2, hpart, counts, list);
    hipLaunchKernelGGL(k_final, dim3(NTOK), dim3(256), 0, stream, x, hpart, b2, ew, pexp, out);
}